// Round 6
// baseline (67.513 us; speedup 1.0000x reference)
//
#include <hip/hip_runtime.h>
#include <math.h>

// Problem constants (from reference setup_inputs):
//   X: (B=32, A=3, S=52, S=52, D=85) f32 ; yboxes: (32,20,4) f32 ;
//   ylabels: (32,20) i32 ; anchors: (3,2) f32 ; nclasses=80
// Reference quirk: wgrid = X.shape[-4] = A = 3 (NOT 52); hgrid = 52.
#define BB    32
#define AA    3
#define SS    52
#define DD    85
#define NN    20
#define NCLS  80
#define KK    (BB * NN)          // 640 boxes
#define WGRID 3
#define HGRID 52
#define HW    (HGRID * WGRID)    // 156 cells
#define BIGV  (1 << 30)
#define NEGINF (-__builtin_inff())
#define NTASK (HW * AA)          // 468 (cell, anchor) wave-tasks
#define NWAVES 16                // block 0: 1024 threads
#define DEPTH  4                 // register pipeline depth (tasks per batch)
#define NBATCH 8                 // 16 waves * 8 * 4 = 512 slots >= 468
#define NPF    14                // prefetch blocks (1920 rows * 7 lines / 1024)

// ---- issue: coalesced row loads for DEPTH tasks into named reg buffers ----
#define ISSUE(bi, E0, E1)                                                     \
  _Pragma("unroll")                                                           \
  for (int d = 0; d < DEPTH; ++d) {                                           \
    const int t    = wv + NWAVES * ((bi) * DEPTH + d);                        \
    const int cell = t / 3;                                                   \
    const int a    = t - 3 * cell;                                            \
    int k = (t < NTASK) ? first[cell < HW ? cell : 0] : BIGV;                 \
    k = (k < BIGV) ? k : 0;      /* dummy row 0 for dead slots */             \
    const float4 bbx = sbox[k];                                               \
    const int x = (int)floorf(bbx.x * (float)WGRID);                          \
    const int y = (int)floorf(bbx.y * (float)HGRID);                          \
    const float* Pp =                                                         \
        X + ((((size_t)(k / NN) * AA + a) * SS + y) * SS + x) * DD;           \
    E0[d] = Pp[lane];                                                         \
    E1[d] = (lane < 21) ? Pp[64 + lane] : NEGINF;                             \
  }

// ---- compute: loss for DEPTH tasks from reg buffers ----
// NOTE: per-task loss is identical on all 64 lanes; ONLY lane 0 accumulates
// (the final reduction sums across lanes — R5's bug was a 64x overcount).
#define COMPUTE(bi, E0, E1)                                                   \
  _Pragma("unroll")                                                           \
  for (int d = 0; d < DEPTH; ++d) {                                           \
    const int t = wv + NWAVES * ((bi) * DEPTH + d);                           \
    if (t < NTASK) {                                                          \
      const int cell = t / 3;                                                 \
      const int a    = t - 3 * cell;                                          \
      const int k    = first[cell];                                           \
      if (k < BIGV) {             /* wave-uniform branch */                   \
        const float e0 = E0[d];                                               \
        const float e1 = E1[d];                                               \
        const float4 bb = sbox[k];                                            \
        const int   lab = slab[k];                                            \
        const float2 anc = sanc[a];                                           \
        const int x = (int)floorf(bb.x * (float)WGRID);                       \
        const int y = (int)floorf(bb.y * (float)HGRID);                       \
        float v = fmaxf((lane >= 5) ? e0 : NEGINF,                            \
                        (lane < 21) ? e1 : NEGINF);                           \
        _Pragma("unroll")                                                     \
        for (int m = 1; m < 64; m <<= 1) v = fmaxf(v, __shfl_xor(v, m, 64));  \
        const float mx = v;                                                   \
        float s = ((lane >= 5) ? expf(e0 - mx) : 0.0f) +                      \
                  ((lane < 21) ? expf(e1 - mx) : 0.0f);                       \
        _Pragma("unroll")                                                     \
        for (int m = 1; m < 64; m <<= 1) s += __shfl_xor(s, m, 64);           \
        const int idx = 5 + lab;                                              \
        const float plab = (idx < 64) ? __shfl(e0, idx, 64)                   \
                                      : __shfl(e1, idx - 64, 64);             \
        const float p0 = __shfl(e0, 0, 64);                                   \
        const float p1 = __shfl(e0, 1, 64);                                   \
        const float p2 = __shfl(e0, 2, 64);                                   \
        const float p3 = __shfl(e0, 3, 64);                                   \
        const float p4 = __shfl(e0, 4, 64);                                   \
        const float z = -p0;                                                  \
        const float obj = fmaxf(z, 0.0f) + log1pf(expf(-fabsf(z)));           \
        const float xrel = bb.x * (float)WGRID - (float)x;                    \
        const float yrel = bb.y * (float)HGRID - (float)y;                    \
        const float wc = bb.z / anc.x;                                        \
        const float hc = bb.w / anc.y;                                        \
        const float d1 = p1 - xrel, d2 = p2 - yrel;                           \
        const float d3 = p3 - wc,   d4 = p4 - hc;                             \
        const float boxl = 0.25f * (d1*d1 + d2*d2 + d3*d3 + d4*d4);           \
        const float clsl = -(plab - mx - logf(s));                            \
        if (lane == 0) acc += obj + 10.0f * boxl + clsl;                      \
      }                                                                       \
    }                                                                         \
  }

// Single regular launch. Block 0 computes everything (LDS prep + pipelined
// wave-tasks + reduce + plain store). Blocks 1..NPF only warm L2/L3 with the
// candidate rows; they write nothing, so block 0's output is independent of
// them (determinism-safe).
__global__ void __launch_bounds__(1024)
yolo_single_kernel(const float* __restrict__ X,
                   const float* __restrict__ yboxes,
                   const int* __restrict__ ylabels,
                   const float* __restrict__ anchors,
                   float* __restrict__ out) {
    const int tid = threadIdx.x;

    if (blockIdx.x != 0) {
        // ---- prefetcher: touch all cachelines of all 1920 candidate rows ----
        const int g  = (int)(blockIdx.x - 1) * 1024 + tid;
        const int t  = g / 7;
        const int ln = g - 7 * t;
        if (t < KK * AA) {
            const int k = t / 3;
            const int a = t - 3 * k;
            const float bx = yboxes[4 * k + 0];
            const float by = yboxes[4 * k + 1];
            const int x = (int)floorf(bx * (float)WGRID);
            const int y = (int)floorf(by * (float)HGRID);
            const float* Pp =
                X + ((((size_t)(k / NN) * AA + a) * SS + y) * SS + x) * DD;
            // float offsets 0,16,32,48,64,80,84 -> every 64B line of the row
            const int off = (ln == 6) ? 84 : ln * 16;
            float vv = Pp[off];
            asm volatile("" :: "v"(vv));   // keep the load alive (rule #17)
        }
        return;
    }

    // ---- block 0: the worker ----
    __shared__ float4 sbox[KK];     // 10 KB
    __shared__ int    slab[KK];     // 2.5 KB
    __shared__ int    first[HW];    // 624 B
    __shared__ float2 sanc[AA];
    __shared__ float  sred[NWAVES];

    if (tid < HW) first[tid] = BIGV;
    if (tid < AA) sanc[tid] = ((const float2*)anchors)[tid];
    __syncthreads();
    if (tid < KK) {
        const float4 b = ((const float4*)yboxes)[tid];
        sbox[tid] = b;
        slab[tid] = ylabels[tid];
        const int x = (int)floorf(b.x * (float)WGRID);   // [0,2]
        const int y = (int)floorf(b.y * (float)HGRID);   // [0,51]
        atomicMin(&first[y * WGRID + x], tid);
    }
    __syncthreads();

    const int wv   = tid >> 6;   // wave id 0..15 (uniform per wave)
    const int lane = tid & 63;
    float acc = 0.0f;

    // depth-4 double-buffered register pipeline over 8 batches
    float A0[DEPTH], A1[DEPTH], B0[DEPTH], B1[DEPTH];
    ISSUE(0, A0, A1)
#pragma unroll
    for (int b = 0; b < NBATCH; b += 2) {
        ISSUE(b + 1, B0, B1)
        COMPUTE(b, A0, A1)
        if (b + 2 < NBATCH) { ISSUE(b + 2, A0, A1) }
        COMPUTE(b + 1, B0, B1)
    }

    // deterministic block reduction, plain store (only lane 0 of each wave
    // holds a nonzero acc, but reducing all lanes is harmless and uniform)
#pragma unroll
    for (int off = 32; off > 0; off >>= 1) acc += __shfl_down(acc, off, 64);
    if (lane == 0) sred[wv] = acc;
    __syncthreads();
    if (wv == 0) {
        float v = (lane < NWAVES) ? sred[lane] : 0.0f;
#pragma unroll
        for (int off = 32; off > 0; off >>= 1) v += __shfl_down(v, off, 64);
        if (lane == 0) out[0] = v;
    }
}

extern "C" void kernel_launch(void* const* d_in, const int* in_sizes, int n_in,
                              void* d_out, int out_size, void* d_ws, size_t ws_size,
                              hipStream_t stream) {
    const float* X       = (const float*)d_in[0];
    const float* yboxes  = (const float*)d_in[1];
    const int*   ylabels = (const int*)d_in[2];
    const float* anchors = (const float*)d_in[3];
    // d_in[4] = nclasses scalar (80), hard-coded above.

    float* out = (float*)d_out;

    yolo_single_kernel<<<1 + NPF, 1024, 0, stream>>>(X, yboxes, ylabels,
                                                     anchors, out);
}

// Round 7
// 17.123 us; speedup vs baseline: 3.9429x; 3.9429x over previous
//
#include <hip/hip_runtime.h>
#include <math.h>

// Problem constants (from reference setup_inputs):
//   X: (B=32, A=3, S=52, S=52, D=85) f32 ; yboxes: (32,20,4) f32 ;
//   ylabels: (32,20) i32 ; anchors: (3,2) f32 ; nclasses=80
// Reference quirk: wgrid = X.shape[-4] = A = 3 (NOT 52); hgrid = 52.
#define BB    32
#define AA    3
#define SS    52
#define DD    85
#define NN    20
#define NCLS  80
#define KK    (BB * NN)          // 640 boxes
#define WGRID 3
#define HGRID 52
#define HW    (HGRID * WGRID)    // 156 cells
#define BIGV  (1 << 30)
#define NEGINF (-__builtin_inff())
#define NTASK (HW * AA)          // 468 (cell, anchor) tasks
#define NTHR  1024
#define NWAVE (NTHR / 64)        // 16 waves
#define NPF   14                 // prefetch blocks (1920 rows * 7 lines / 1024)

// Dynamic LDS layout: rows[NTASK*DD] floats, then saddr[NTASK] pointers.
#define ROWS_FLOATS (NTASK * DD)                       // 39780 floats
#define DYN_BYTES   (ROWS_FLOATS * 4 + NTASK * 8)      // 159120 + 3744 = 162864

// Single regular launch.
// Block 0: prep (first-claim in LDS) -> parallel row-pointer calc ->
//          coalesced LDS row staging -> per-thread task math (no shuffles) ->
//          deterministic tree reduce -> plain store.
// Blocks 1..NPF: read-only L2/L3 warmers for the candidate rows (X is evicted
// by the harness's 345MB poison fills between replays); they write nothing, so
// block 0's result is independent of them.
__global__ void __launch_bounds__(NTHR)
yolo_onecu_kernel(const float* __restrict__ X,
                  const float* __restrict__ yboxes,
                  const int* __restrict__ ylabels,
                  const float* __restrict__ anchors,
                  float* __restrict__ out) {
    const int tid = threadIdx.x;

    if (blockIdx.x != 0) {
        // ---- prefetcher: touch all cachelines of all 1920 candidate rows ----
        const int g  = (int)(blockIdx.x - 1) * NTHR + tid;
        const int t  = g / 7;
        const int ln = g - 7 * t;
        if (t < KK * AA) {
            const int k = t / 3;
            const int a = t - 3 * k;
            const float bx = yboxes[4 * k + 0];
            const float by = yboxes[4 * k + 1];
            const int x = (int)floorf(bx * (float)WGRID);
            const int y = (int)floorf(by * (float)HGRID);
            const float* P =
                X + ((((size_t)(k / NN) * AA + a) * SS + y) * SS + x) * DD;
            const int off = (ln == 6) ? 84 : ln * 16;   // every 64B line
            float vv = P[off];
            asm volatile("" :: "v"(vv));   // keep load alive (rule #17)
        }
        return;
    }

    // ---- block 0: the worker ----
    extern __shared__ unsigned char dynlds[];
    float* rows = (float*)dynlds;                               // [NTASK][85]
    const float** saddr = (const float**)(dynlds + ROWS_FLOATS * 4);
    __shared__ int   first[HW];
    __shared__ float sred[NWAVE];

    const int lane = tid & 63;
    const int wv   = tid >> 6;

    // phase 1: first-claim scatter-min
    if (tid < HW) first[tid] = BIGV;
    __syncthreads();
    if (tid < KK) {
        const float4 b = ((const float4*)yboxes)[tid];
        const int x = (int)floorf(b.x * (float)WGRID);   // [0,2]
        const int y = (int)floorf(b.y * (float)HGRID);   // [0,51]
        atomicMin(&first[y * WGRID + x], tid);
    }
    __syncthreads();

    // phase 2a: all 468 row pointers computed in parallel (one chain deep).
    // Dead cells get a dummy pointer (row 0) and are staged harmlessly.
    if (tid < NTASK) {
        const int cell = tid / 3;
        const int a    = tid - 3 * cell;
        int k = first[cell];
        k = (k < BIGV) ? k : 0;
        const float bx = yboxes[4 * k + 0];
        const float by = yboxes[4 * k + 1];
        const int x = (int)floorf(bx * (float)WGRID);
        const int y = (int)floorf(by * (float)HGRID);
        saddr[tid] = X + ((((size_t)(k / NN) * AA + a) * SS + y) * SS + x) * DD;
    }
    __syncthreads();

    // phase 2b: coalesced staging; wave wv streams rows wv, wv+16, ...
    // Independent iterations -> compiler software-pipelines the global loads.
#pragma unroll 5
    for (int t = wv; t < NTASK; t += NWAVE) {
        const float* P = saddr[t];        // same addr across lanes: broadcast
        float* dst = rows + t * DD;
        dst[lane] = P[lane];                       // lanes 0..63
        if (lane < DD - 64) dst[64 + lane] = P[64 + lane];   // lanes 0..20
    }
    __syncthreads();

    // phase 3: per-thread task math from LDS (lane stride 85 = 2-way bank
    // aliasing = free). No cross-lane ops at all.
    float per = 0.0f;
    if (tid < NTASK) {
        const int cell = tid / 3;
        const int a    = tid - 3 * cell;
        const int k    = first[cell];
        if (k < BIGV) {
            const float4 bbv = ((const float4*)yboxes)[k];
            const int   lab  = ylabels[k];
            const float2 anc = ((const float2*)anchors)[a];
            const int x = (int)floorf(bbv.x * (float)WGRID);
            const int y = (int)floorf(bbv.y * (float)HGRID);
            const float* p = rows + tid * DD;

            const float p0 = p[0], p1 = p[1], p2 = p[2], p3 = p[3], p4 = p[4];

            float mx = p[5];
#pragma unroll
            for (int c = 6; c < DD; ++c) mx = fmaxf(mx, p[c]);
            float s = 0.0f;
#pragma unroll
            for (int c = 5; c < DD; ++c) s += __expf(p[c] - mx);
            const float plab = p[5 + lab];   // dynamic index into LDS: fine

            // obj = softplus(-p0), numerically stable (matches jax)
            const float z = -p0;
            const float obj = fmaxf(z, 0.0f) + log1pf(__expf(-fabsf(z)));

            // box MSE vs target
            const float xrel = bbv.x * (float)WGRID - (float)x;
            const float yrel = bbv.y * (float)HGRID - (float)y;
            const float wc = bbv.z / anc.x;
            const float hc = bbv.w / anc.y;
            const float d1 = p1 - xrel, d2 = p2 - yrel;
            const float d3 = p3 - wc,   d4 = p4 - hc;
            const float boxl = 0.25f * (d1 * d1 + d2 * d2 + d3 * d3 + d4 * d4);

            // class NLL
            const float clsl = -(plab - mx - __logf(s));

            per = obj + 10.0f * boxl + clsl;
        }
    }

    // deterministic block reduction, plain store
#pragma unroll
    for (int off = 32; off > 0; off >>= 1) per += __shfl_down(per, off, 64);
    if (lane == 0) sred[wv] = per;
    __syncthreads();
    if (wv == 0) {
        float v = (lane < NWAVE) ? sred[lane] : 0.0f;
#pragma unroll
        for (int off = 8; off > 0; off >>= 1) v += __shfl_down(v, off, 64);
        if (lane == 0) out[0] = v;
    }
}

extern "C" void kernel_launch(void* const* d_in, const int* in_sizes, int n_in,
                              void* d_out, int out_size, void* d_ws, size_t ws_size,
                              hipStream_t stream) {
    const float* X       = (const float*)d_in[0];
    const float* yboxes  = (const float*)d_in[1];
    const int*   ylabels = (const int*)d_in[2];
    const float* anchors = (const float*)d_in[3];
    // d_in[4] = nclasses scalar (80), hard-coded above.

    float* out = (float*)d_out;

    // opt-in to >64KB dynamic LDS (gfx950 allows up to 160KB/workgroup)
    (void)hipFuncSetAttribute((const void*)yolo_onecu_kernel,
                              hipFuncAttributeMaxDynamicSharedMemorySize,
                              DYN_BYTES);

    yolo_onecu_kernel<<<1 + NPF, NTHR, DYN_BYTES, stream>>>(X, yboxes, ylabels,
                                                            anchors, out);
}